// Round 1
// baseline (552.398 us; speedup 1.0000x reference)
//
#include <hip/hip_runtime.h>

// Sizes fixed by the problem.
#define BB 32
#define TT 512
#define VV 1024
#define HH 256

typedef float f32x4 __attribute__((ext_vector_type(4)));
typedef _Float16 f16x8 __attribute__((ext_vector_type(8)));
typedef _Float16 f16x4 __attribute__((ext_vector_type(4)));

__device__ __forceinline__ float tanh_fast(float x) {
  // tanh(x) = 1 - 2/(exp(2x)+1); exp(2x) = 2^(x * 2*log2(e))
  float e = __builtin_amdgcn_exp2f(x * 2.885390081777927f);
  return 1.0f - 2.0f * __builtin_amdgcn_rcpf(e + 1.0f);
}

// ---------------------------------------------------------------------------
// Transpose + cast fp32 -> f16:  out[C][R] = (f16) in[R][C]
// grid (C/32, R/32), block 256
// ---------------------------------------------------------------------------
__global__ __launch_bounds__(256) void k_transpose_cast(
    const float* __restrict__ in, _Float16* __restrict__ outp, int R, int C)
{
  __shared__ float tile[32][33];
  const int tx = threadIdx.x & 31, ty = threadIdx.x >> 5;
  const int tc = blockIdx.x * 32, tr = blockIdx.y * 32;
#pragma unroll
  for (int i = 0; i < 32; i += 8)
    tile[ty + i][tx] = in[(size_t)(tr + ty + i) * C + tc + tx];
  __syncthreads();
#pragma unroll
  for (int i = 0; i < 32; i += 8)
    outp[(size_t)(tc + ty + i) * R + tr + tx] = (_Float16)tile[tx][ty + i];
}

// ---------------------------------------------------------------------------
// GEMM1: xproj[t][b][h] = X[b][t][:] @ Wx[:][h] + bias[h]
// A = X fp32 [16384][1024] (cast to f16 in staging), B = WxT f16 [256][1024]
// BM=64, BN=256(full), BK=64. block 256 (4 waves), grid 256.
// ---------------------------------------------------------------------------
__global__ __launch_bounds__(256) void k_gemm1(
    const float* __restrict__ X, const _Float16* __restrict__ WxT,
    const float* __restrict__ bias, float* __restrict__ xproj)
{
  __shared__ _Float16 As[64][72];
  __shared__ _Float16 Bs[256][72];
  const int tid = threadIdx.x;
  const int lane = tid & 63, w = tid >> 6;
  const int l15 = lane & 15, lq = lane >> 4;
  const int m0 = blockIdx.x * 64;

  f32x4 acc[16];
#pragma unroll
  for (int i = 0; i < 16; ++i) acc[i] = (f32x4){0.f, 0.f, 0.f, 0.f};

  for (int kc = 0; kc < 16; ++kc) {
    const int k0 = kc * 64;
    // stage A (64x64 fp32 -> f16)
#pragma unroll
    for (int it = 0; it < 4; ++it) {
      int q = tid + it * 256;          // 0..1023
      int r = q >> 4, k4 = (q & 15) * 4;
      f32x4 v = *(const f32x4*)(X + (size_t)(m0 + r) * 1024 + k0 + k4);
      f16x4 hv;
      hv[0] = (_Float16)v[0]; hv[1] = (_Float16)v[1];
      hv[2] = (_Float16)v[2]; hv[3] = (_Float16)v[3];
      *(f16x4*)(&As[r][k4]) = hv;
    }
    // stage B (256x64 f16, from WxT rows = output cols)
#pragma unroll
    for (int it = 0; it < 8; ++it) {
      int q = tid + it * 256;          // 0..2047
      int n = q >> 3, k8 = (q & 7) * 8;
      *(f16x8*)(&Bs[n][k8]) = *(const f16x8*)(WxT + (size_t)n * 1024 + k0 + k8);
    }
    __syncthreads();
    f16x8 a[2];
#pragma unroll
    for (int ks = 0; ks < 2; ++ks)
      a[ks] = *(const f16x8*)(&As[w * 16 + l15][ks * 32 + lq * 8]);
#pragma unroll
    for (int ct = 0; ct < 16; ++ct) {
#pragma unroll
      for (int ks = 0; ks < 2; ++ks) {
        f16x8 bfr = *(const f16x8*)(&Bs[ct * 16 + l15][ks * 32 + lq * 8]);
        acc[ct] = __builtin_amdgcn_mfma_f32_16x16x32_f16(a[ks], bfr, acc[ct], 0, 0, 0);
      }
    }
    __syncthreads();
  }
  // epilogue: +bias, write xproj in [t][b][h] order
#pragma unroll
  for (int ct = 0; ct < 16; ++ct) {
    int ncol = ct * 16 + l15;
    float bvv = bias[ncol];
#pragma unroll
    for (int r = 0; r < 4; ++r) {
      int m = m0 + w * 16 + lq * 4 + r;     // m = b*512 + t
      int tt = m & 511, bb = m >> 9;
      xproj[(size_t)(tt * 32 + bb) * 256 + ncol] = acc[ct][r] + bvv;
    }
  }
}

// ---------------------------------------------------------------------------
// RNN scan: h_t = tanh(xproj[t] + h_{t-1} @ Wh).  2 blocks x 16 batches.
// 8 waves; wave w owns output cols [w*32, w*32+32). Wh^T fragments in regs.
// h ping-pongs in LDS (f16, XOR-swizzled). Y written f16 [b][t][h];
// final h written fp32 to hT.
// ---------------------------------------------------------------------------
__global__ __launch_bounds__(512) void k_scan(
    const float* __restrict__ xproj,   // [512][32][256]
    const _Float16* __restrict__ WhT,  // [256][256]  (WhT[j][k] = Wh[k][j])
    _Float16* __restrict__ Y,          // [16384][256]  row = b*512+t
    float* __restrict__ hT)            // [32][256]
{
  __shared__ _Float16 hbuf[2][16 * 256];
  const int tid = threadIdx.x;
  const int lane = tid & 63, w = tid >> 6;
  const int l15 = lane & 15, lq = lane >> 4;
  const int g = blockIdx.x;            // batch group: batches g*16..g*16+15

  for (int i = tid; i < 2 * 4096; i += 512) ((_Float16*)hbuf)[i] = (_Float16)0.f;

  // Wh fragments: bf[ct][ks] covers cols w*32+ct*16+(l15), k = ks*32+lq*8..+8
  f16x8 bf0[8], bf1[8];
  {
    int col0 = w * 32 + l15;
    int col1 = w * 32 + 16 + l15;
#pragma unroll
    for (int ks = 0; ks < 8; ++ks) {
      bf0[ks] = *(const f16x8*)(WhT + col0 * 256 + ks * 32 + lq * 8);
      bf1[ks] = *(const f16x8*)(WhT + col1 * 256 + ks * 32 + lq * 8);
    }
  }
  __syncthreads();

  const int col0 = w * 32 + l15;
  const int col1 = w * 32 + 16 + l15;
  float hprev0[4], hprev1[4];          // previous step's h (for deferred stores)

  for (int t = 0; t < 512; ++t) {
    const int cur = t & 1;
    // deferred global stores of h_{t-1} (overlap with this step's compute)
    if (t > 0) {
#pragma unroll
      for (int r = 0; r < 4; ++r) {
        int b = g * 16 + lq * 4 + r;
        Y[((size_t)b * 512 + (t - 1)) * 256 + col0] = (_Float16)hprev0[r];
        Y[((size_t)b * 512 + (t - 1)) * 256 + col1] = (_Float16)hprev1[r];
      }
    }
    // xp prefetch
    const float* xpt = xproj + (size_t)(t * 32 + g * 16) * 256;
    float xp0[4], xp1[4];
#pragma unroll
    for (int r = 0; r < 4; ++r) {
      xp0[r] = xpt[(lq * 4 + r) * 256 + col0];
      xp1[r] = xpt[(lq * 4 + r) * 256 + col1];
    }
    // A fragments from LDS (swizzled)
    f16x8 af[8];
    const char* hb = (const char*)hbuf[cur];
#pragma unroll
    for (int ks = 0; ks < 8; ++ks) {
      int off = (l15 * 512 + ks * 64 + lq * 16) ^ ((l15 & 7) << 4);
      af[ks] = *(const f16x8*)(hb + off);
    }
    f32x4 acc0 = {0.f, 0.f, 0.f, 0.f}, acc1 = {0.f, 0.f, 0.f, 0.f};
#pragma unroll
    for (int ks = 0; ks < 8; ++ks) {
      acc0 = __builtin_amdgcn_mfma_f32_16x16x32_f16(af[ks], bf0[ks], acc0, 0, 0, 0);
      acc1 = __builtin_amdgcn_mfma_f32_16x16x32_f16(af[ks], bf1[ks], acc1, 0, 0, 0);
    }
    // epilogue: tanh, write h_t to the other LDS buffer
    char* hn = (char*)hbuf[cur ^ 1];
#pragma unroll
    for (int r = 0; r < 4; ++r) {
      int row = lq * 4 + r;
      float v0 = tanh_fast(acc0[r] + xp0[r]);
      float v1 = tanh_fast(acc1[r] + xp1[r]);
      int o0 = (row * 512 + col0 * 2) ^ ((row & 7) << 4);
      int o1 = (row * 512 + col1 * 2) ^ ((row & 7) << 4);
      *(_Float16*)(hn + o0) = (_Float16)v0;
      *(_Float16*)(hn + o1) = (_Float16)v1;
      hprev0[r] = v0;
      hprev1[r] = v1;
    }
    __syncthreads();
  }
  // tail: store h_511 to Y and final state (fp32)
#pragma unroll
  for (int r = 0; r < 4; ++r) {
    int b = g * 16 + lq * 4 + r;
    Y[((size_t)b * 512 + 511) * 256 + col0] = (_Float16)hprev0[r];
    Y[((size_t)b * 512 + 511) * 256 + col1] = (_Float16)hprev1[r];
    hT[b * 256 + col0] = hprev0[r];
    hT[b * 256 + col1] = hprev1[r];
  }
}

// ---------------------------------------------------------------------------
// GEMM3 + fused softmax: out = softmax(Y @ Wd + bd)
// One block per 16 output rows; 8 waves; full N=1024 row kept in LDS (f16).
// ---------------------------------------------------------------------------
__global__ __launch_bounds__(512) void k_gemm3(
    const _Float16* __restrict__ Y,    // [16384][256]
    const _Float16* __restrict__ WdT,  // [1024][256]  (WdT[n][k] = Wd[k][n])
    const float* __restrict__ bd,      // [1024]
    float* __restrict__ out)           // [16384][1024]
{
  __shared__ _Float16 As[16][264];
  __shared__ _Float16 Bs[128][264];
  __shared__ _Float16 lg[16][1040];
  const int tid = threadIdx.x;
  const int lane = tid & 63, w = tid >> 6;
  const int l15 = lane & 15, lq = lane >> 4;
  const int m0 = blockIdx.x * 16;

  // stage A rows (16 x 256 f16)
  {
    int r = tid >> 5, k8 = (tid & 31) * 8;
    *(f16x8*)(&As[r][k8]) = *(const f16x8*)(Y + (size_t)(m0 + r) * 256 + k8);
  }
  __syncthreads();
  f16x8 a[8];
#pragma unroll
  for (int ks = 0; ks < 8; ++ks)
    a[ks] = *(const f16x8*)(&As[l15][ks * 32 + lq * 8]);

  for (int cc = 0; cc < 8; ++cc) {
    const int c0 = cc * 128;
    __syncthreads();                     // protect Bs from prior chunk's readers
#pragma unroll
    for (int i = 0; i < 8; ++i) {
      int q = i * 512 + tid;             // 0..4095
      int n = q >> 5, k8 = (q & 31) * 8;
      *(f16x8*)(&Bs[n][k8]) = *(const f16x8*)(WdT + (size_t)(c0 + n) * 256 + k8);
    }
    __syncthreads();
    int ncol = c0 + w * 16 + l15;
    f32x4 acc = {0.f, 0.f, 0.f, 0.f};
#pragma unroll
    for (int ks = 0; ks < 8; ++ks) {
      f16x8 bfr = *(const f16x8*)(&Bs[w * 16 + l15][ks * 32 + lq * 8]);
      acc = __builtin_amdgcn_mfma_f32_16x16x32_f16(a[ks], bfr, acc, 0, 0, 0);
    }
    float bvv = bd[ncol];
#pragma unroll
    for (int r = 0; r < 4; ++r)
      lg[lq * 4 + r][ncol] = (_Float16)(acc[r] + bvv);
  }
  __syncthreads();

  // softmax: 16 rows x 32 threads each
  const int row = tid >> 5, j = tid & 31;
  float mx = -1e30f;
#pragma unroll
  for (int k = 0; k < 32; ++k)
    mx = fmaxf(mx, (float)lg[row][j + k * 32]);
#pragma unroll
  for (int m = 1; m < 32; m <<= 1)
    mx = fmaxf(mx, __shfl_xor(mx, m, 64));
  float s = 0.f;
#pragma unroll
  for (int k = 0; k < 32; ++k)
    s += __builtin_amdgcn_exp2f(((float)lg[row][j + k * 32] - mx) * 1.44269504088896f);
#pragma unroll
  for (int m = 1; m < 32; m <<= 1)
    s += __shfl_xor(s, m, 64);
  const float rinv = __builtin_amdgcn_rcpf(s);
  float* orow = out + (size_t)(m0 + row) * 1024;
#pragma unroll
  for (int k = 0; k < 8; ++k) {
    int c = k * 128 + j * 4;
    f32x4 vv;
#pragma unroll
    for (int u = 0; u < 4; ++u)
      vv[u] = __builtin_amdgcn_exp2f(((float)lg[row][c + u] - mx) * 1.44269504088896f) * rinv;
    *(f32x4*)(orow + c) = vv;
  }
}

// ---------------------------------------------------------------------------
extern "C" void kernel_launch(void* const* d_in, const int* in_sizes, int n_in,
                              void* d_out, int out_size, void* d_ws, size_t ws_size,
                              hipStream_t stream) {
  const float* X  = (const float*)d_in[0];   // [32][512][1024]
  const float* Wx = (const float*)d_in[1];   // [1024][256]
  const float* Wh = (const float*)d_in[2];   // [256][256]
  const float* bv = (const float*)d_in[3];   // [256]
  const float* Wd = (const float*)d_in[4];   // [256][1024]
  const float* bd = (const float*)d_in[5];   // [1024]
  float* out = (float*)d_out;                // [16384*1024] softmax + [32*256] state

  char* ws = (char*)d_ws;
  float*    xproj = (float*)(ws);                                  // 16 MB
  _Float16* Yh    = (_Float16*)(ws + (16u << 20));                 // 8 MB
  _Float16* WxT   = (_Float16*)(ws + (24u << 20));                 // 512 KB
  _Float16* WhT   = (_Float16*)(ws + (24u << 20) + (512u << 10));  // 128 KB
  _Float16* WdT   = (_Float16*)(ws + (24u << 20) + (640u << 10));  // 512 KB

  k_transpose_cast<<<dim3(8, 32), 256, 0, stream>>>(Wx, WxT, 1024, 256);
  k_transpose_cast<<<dim3(8, 8),  256, 0, stream>>>(Wh, WhT, 256, 256);
  k_transpose_cast<<<dim3(32, 8), 256, 0, stream>>>(Wd, WdT, 256, 1024);
  k_gemm1<<<dim3(256), 256, 0, stream>>>(X, WxT, bv, xproj);
  k_scan<<<dim3(2), 512, 0, stream>>>(xproj, WhT, Yh, out + 16384 * 1024);
  k_gemm3<<<dim3(1024), 512, 0, stream>>>(Yh, WdT, bd, out);
}

// Round 2
// 445.771 us; speedup vs baseline: 1.2392x; 1.2392x over previous
//
#include <hip/hip_runtime.h>

// Sizes fixed by the problem.
#define BB 32
#define TT 512
#define VV 1024
#define HH 256

typedef float f32x4 __attribute__((ext_vector_type(4)));
typedef _Float16 f16x8 __attribute__((ext_vector_type(8)));
typedef _Float16 f16x4 __attribute__((ext_vector_type(4)));

__device__ __forceinline__ float tanh_fast(float x) {
  // tanh(x) = 1 - 2/(exp(2x)+1); exp(2x) = 2^(x * 2*log2(e))
  float e = __builtin_amdgcn_exp2f(x * 2.885390081777927f);
  return 1.0f - 2.0f * __builtin_amdgcn_rcpf(e + 1.0f);
}

// ---------------------------------------------------------------------------
// Transpose + cast fp32 -> f16:  out[C][R] = (f16) in[R][C]
// ---------------------------------------------------------------------------
__global__ __launch_bounds__(256) void k_transpose_cast(
    const float* __restrict__ in, _Float16* __restrict__ outp, int R, int C)
{
  __shared__ float tile[32][33];
  const int tx = threadIdx.x & 31, ty = threadIdx.x >> 5;
  const int tc = blockIdx.x * 32, tr = blockIdx.y * 32;
#pragma unroll
  for (int i = 0; i < 32; i += 8)
    tile[ty + i][tx] = in[(size_t)(tr + ty + i) * C + tc + tx];
  __syncthreads();
#pragma unroll
  for (int i = 0; i < 32; i += 8)
    outp[(size_t)(tc + ty + i) * R + tr + tx] = (_Float16)tile[tx][ty + i];
}

// ---------------------------------------------------------------------------
// GEMM1: xproj = X @ Wx + b, written PACKED for the scan kernel:
//   xp_packed[((t*2+g)*8 + w)*512 + lane*8 + set*4 + r]
//     where b = g*16 + (lane>>4)*4 + r, col = w*32 + set*16 + (lane&15)
// ---------------------------------------------------------------------------
__global__ __launch_bounds__(256) void k_gemm1(
    const float* __restrict__ X, const _Float16* __restrict__ WxT,
    const float* __restrict__ bias, float* __restrict__ xp_packed)
{
  __shared__ _Float16 As[64][72];
  __shared__ _Float16 Bs[256][72];
  const int tid = threadIdx.x;
  const int lane = tid & 63, w = tid >> 6;
  const int l15 = lane & 15, lq = lane >> 4;
  const int m0 = blockIdx.x * 64;

  f32x4 acc[16];
#pragma unroll
  for (int i = 0; i < 16; ++i) acc[i] = (f32x4){0.f, 0.f, 0.f, 0.f};

  for (int kc = 0; kc < 16; ++kc) {
    const int k0 = kc * 64;
#pragma unroll
    for (int it = 0; it < 4; ++it) {
      int q = tid + it * 256;
      int r = q >> 4, k4 = (q & 15) * 4;
      f32x4 v = *(const f32x4*)(X + (size_t)(m0 + r) * 1024 + k0 + k4);
      f16x4 hv;
      hv[0] = (_Float16)v[0]; hv[1] = (_Float16)v[1];
      hv[2] = (_Float16)v[2]; hv[3] = (_Float16)v[3];
      *(f16x4*)(&As[r][k4]) = hv;
    }
#pragma unroll
    for (int it = 0; it < 8; ++it) {
      int q = tid + it * 256;
      int n = q >> 3, k8 = (q & 7) * 8;
      *(f16x8*)(&Bs[n][k8]) = *(const f16x8*)(WxT + (size_t)n * 1024 + k0 + k8);
    }
    __syncthreads();
    f16x8 a[2];
#pragma unroll
    for (int ks = 0; ks < 2; ++ks)
      a[ks] = *(const f16x8*)(&As[w * 16 + l15][ks * 32 + lq * 8]);
#pragma unroll
    for (int ct = 0; ct < 16; ++ct) {
#pragma unroll
      for (int ks = 0; ks < 2; ++ks) {
        f16x8 bfr = *(const f16x8*)(&Bs[ct * 16 + l15][ks * 32 + lq * 8]);
        acc[ct] = __builtin_amdgcn_mfma_f32_16x16x32_f16(a[ks], bfr, acc[ct], 0, 0, 0);
      }
    }
    __syncthreads();
  }
  // epilogue: +bias, scatter into scan-packed layout
#pragma unroll
  for (int ct = 0; ct < 16; ++ct) {
    int ncol = ct * 16 + l15;
    float bvv = bias[ncol];
    int ws2 = ncol >> 5, set = (ncol >> 4) & 1, c15 = ncol & 15;
#pragma unroll
    for (int r = 0; r < 4; ++r) {
      int m = m0 + w * 16 + lq * 4 + r;     // m = b*512 + t
      int tt = m & 511, bb = m >> 9;
      int g2 = bb >> 4, lq2 = (bb >> 2) & 3, r2 = bb & 3;
      size_t off = ((((size_t)tt * 2 + g2) * 8 + ws2) * 64 + (lq2 * 16 + c15)) * 8
                   + set * 4 + r2;
      xp_packed[off] = acc[ct][r] + bvv;
    }
  }
}

// ---------------------------------------------------------------------------
// RNN scan, latency-optimized:
//  - raw barrier (lgkmcnt(0) only) -> global loads/stores stay in flight
//  - xp prefetched 2 steps ahead as 2x dwordx4, consumed as MFMA acc init
//  - Y flushed via LDS re-read: 1 ds_read_b128 + 1 global_store_dwordx4
//  - MFMA chain split 4+4
// 2 blocks x 512 threads; block g owns batches g*16..g*16+15.
// ---------------------------------------------------------------------------
__global__ __launch_bounds__(512) void k_scan(
    const float* __restrict__ xp_packed,  // packed, see k_gemm1
    const _Float16* __restrict__ WhT,     // [256][256]
    _Float16* __restrict__ Yt,            // [512][32][256] f16  (t-major!)
    float* __restrict__ hT)               // [32][256] fp32
{
  __shared__ _Float16 hbuf[2][16 * 256];
  const int tid = threadIdx.x;
  const int lane = tid & 63, w = tid >> 6;
  const int l15 = lane & 15, lq = lane >> 4;
  const int g = blockIdx.x;

  for (int i = tid; i < 2 * 4096; i += 512) ((_Float16*)hbuf)[i] = (_Float16)0.f;

  const int col0 = w * 32 + l15;
  const int col1 = col0 + 16;

  // Wh fragments in registers for the whole scan
  f16x8 bf0[8], bf1[8];
#pragma unroll
  for (int ks = 0; ks < 8; ++ks) {
    bf0[ks] = *(const f16x8*)(WhT + col0 * 256 + ks * 32 + lq * 8);
    bf1[ks] = *(const f16x8*)(WhT + col1 * 256 + ks * 32 + lq * 8);
  }

  // Y-flush addressing: thread tid flushes 16B at linear byte p=tid*16 of the
  // 16x256 f16 h tile; swizzle-corrected LDS offset, row/col for global store.
  const int frow = tid >> 5;             // batch row 0..15
  const int fcol8 = (tid & 31) * 8;      // h col (x8)
  const int flds = (tid * 16) ^ (((tid >> 5) & 7) << 4);

  // per-lane xp base (packed layout), stride 8192 floats per step
  const float* xpbase = xp_packed + (size_t)g * 4096 + w * 512 + lane * 8;

  __syncthreads();   // one full barrier after zero-init (vmcnt drain OK here)

  // prefetch xp for t=0,1
  f32x4 xa0 = *(const f32x4*)(xpbase);
  f32x4 xb0 = *(const f32x4*)(xpbase + 4);
  f32x4 xa1 = *(const f32x4*)(xpbase + 8192);
  f32x4 xb1 = *(const f32x4*)(xpbase + 8192 + 4);

  float* hTrow = hT + (g * 16 + frow) * 256 + fcol8;

#define SCAN_STEP(T, CUR, XA, XB)                                              \
  {                                                                            \
    const int t = (T);                                                         \
    const char* hb = (const char*)hbuf[CUR];                                   \
    char* hn = (char*)hbuf[(CUR) ^ 1];                                         \
    if (t > 0) { /* flush h_{t-1} (same buffer we read this step) */           \
      f16x8 hv = *(const f16x8*)(hb + flds);                                   \
      *(f16x8*)(Yt + ((size_t)(t - 1) * 32 + g * 16 + frow) * 256 + fcol8) = hv; \
    }                                                                          \
    f16x8 af[8];                                                               \
    _Pragma("unroll")                                                          \
    for (int ks = 0; ks < 8; ++ks) {                                           \
      int off = (l15 * 512 + ks * 64 + lq * 16) ^ ((l15 & 7) << 4);            \
      af[ks] = *(const f16x8*)(hb + off);                                      \
    }                                                                          \
    f32x4 acc0a = XA, acc1a = XB;                                              \
    f32x4 acc0b = {0.f, 0.f, 0.f, 0.f}, acc1b = {0.f, 0.f, 0.f, 0.f};          \
    { /* prefetch xp for t+2 into the just-freed regs */                       \
      int tn = (t + 2 < 512) ? t + 2 : 510;                                    \
      const float* p = xpbase + (size_t)tn * 8192;                             \
      XA = *(const f32x4*)p;                                                   \
      XB = *(const f32x4*)(p + 4);                                             \
    }                                                                          \
    _Pragma("unroll")                                                          \
    for (int ks = 0; ks < 4; ++ks) {                                           \
      acc0a = __builtin_amdgcn_mfma_f32_16x16x32_f16(af[ks], bf0[ks], acc0a, 0, 0, 0); \
      acc1a = __builtin_amdgcn_mfma_f32_16x16x32_f16(af[ks], bf1[ks], acc1a, 0, 0, 0); \
      acc0b = __builtin_amdgcn_mfma_f32_16x16x32_f16(af[ks + 4], bf0[ks + 4], acc0b, 0, 0, 0); \
      acc1b = __builtin_amdgcn_mfma_f32_16x16x32_f16(af[ks + 4], bf1[ks + 4], acc1b, 0, 0, 0); \
    }                                                                          \
    _Pragma("unroll")                                                          \
    for (int r = 0; r < 4; ++r) {                                              \
      int row = lq * 4 + r;                                                    \
      float v0 = tanh_fast(acc0a[r] + acc0b[r]);                               \
      float v1 = tanh_fast(acc1a[r] + acc1b[r]);                               \
      int o0 = (row * 512 + col0 * 2) ^ ((row & 7) << 4);                      \
      int o1 = (row * 512 + col1 * 2) ^ ((row & 7) << 4);                      \
      *(_Float16*)(hn + o0) = (_Float16)v0;                                    \
      *(_Float16*)(hn + o1) = (_Float16)v1;                                    \
    }                                                                          \
    asm volatile("s_waitcnt lgkmcnt(0)" ::: "memory");                         \
    __builtin_amdgcn_s_barrier();                                              \
    asm volatile("" ::: "memory");                                             \
  }

  for (int tp = 0; tp < 256; ++tp) {
    SCAN_STEP(tp * 2,     0, xa0, xb0)
    SCAN_STEP(tp * 2 + 1, 1, xa1, xb1)
  }
#undef SCAN_STEP

  // h_511 sits in hbuf[0]; flush to Yt[511] and final state (fp32)
  {
    f16x8 hv = *(const f16x8*)(((const char*)hbuf[0]) + flds);
    *(f16x8*)(Yt + ((size_t)511 * 32 + g * 16 + frow) * 256 + fcol8) = hv;
    f32x4 lo, hi;
#pragma unroll
    for (int u = 0; u < 4; ++u) { lo[u] = (float)hv[u]; hi[u] = (float)hv[u + 4]; }
    *(f32x4*)(hTrow) = lo;
    *(f32x4*)(hTrow + 4) = hi;
  }
}

// ---------------------------------------------------------------------------
// GEMM3 + fused softmax: out = softmax(Y @ Wd + bd)
// A rows come from Yt in [t][b][h] order: row m=b*512+t -> Yt[(t)*32+b].
// ---------------------------------------------------------------------------
__global__ __launch_bounds__(512) void k_gemm3(
    const _Float16* __restrict__ Yt,   // [512][32][256]
    const _Float16* __restrict__ WdT,  // [1024][256]
    const float* __restrict__ bd,      // [1024]
    float* __restrict__ out)           // [16384][1024]
{
  __shared__ _Float16 As[16][264];
  __shared__ _Float16 Bs[128][264];
  __shared__ _Float16 lg[16][1040];
  const int tid = threadIdx.x;
  const int lane = tid & 63, w = tid >> 6;
  const int l15 = lane & 15, lq = lane >> 4;
  const int m0 = blockIdx.x * 16;
  const int b = m0 >> 9, t0 = m0 & 511;   // 16 rows = same batch, consecutive t

  {
    int r = tid >> 5, k8 = (tid & 31) * 8;
    *(f16x8*)(&As[r][k8]) = *(const f16x8*)(Yt + ((size_t)(t0 + r) * 32 + b) * 256 + k8);
  }
  __syncthreads();
  f16x8 a[8];
#pragma unroll
  for (int ks = 0; ks < 8; ++ks)
    a[ks] = *(const f16x8*)(&As[l15][ks * 32 + lq * 8]);

  for (int cc = 0; cc < 8; ++cc) {
    const int c0 = cc * 128;
    __syncthreads();
#pragma unroll
    for (int i = 0; i < 8; ++i) {
      int q = i * 512 + tid;
      int n = q >> 5, k8 = (q & 31) * 8;
      *(f16x8*)(&Bs[n][k8]) = *(const f16x8*)(WdT + (size_t)(c0 + n) * 256 + k8);
    }
    __syncthreads();
    int ncol = c0 + w * 16 + l15;
    f32x4 acc = {0.f, 0.f, 0.f, 0.f};
#pragma unroll
    for (int ks = 0; ks < 8; ++ks) {
      f16x8 bfr = *(const f16x8*)(&Bs[w * 16 + l15][ks * 32 + lq * 8]);
      acc = __builtin_amdgcn_mfma_f32_16x16x32_f16(a[ks], bfr, acc, 0, 0, 0);
    }
    float bvv = bd[ncol];
#pragma unroll
    for (int r = 0; r < 4; ++r)
      lg[lq * 4 + r][ncol] = (_Float16)(acc[r] + bvv);
  }
  __syncthreads();

  const int row = tid >> 5, j = tid & 31;
  float mx = -1e30f;
#pragma unroll
  for (int k = 0; k < 32; ++k)
    mx = fmaxf(mx, (float)lg[row][j + k * 32]);
#pragma unroll
  for (int m = 1; m < 32; m <<= 1)
    mx = fmaxf(mx, __shfl_xor(mx, m, 64));
  float s = 0.f;
#pragma unroll
  for (int k = 0; k < 32; ++k)
    s += __builtin_amdgcn_exp2f(((float)lg[row][j + k * 32] - mx) * 1.44269504088896f);
#pragma unroll
  for (int m = 1; m < 32; m <<= 1)
    s += __shfl_xor(s, m, 64);
  const float rinv = __builtin_amdgcn_rcpf(s);
  float* orow = out + (size_t)(m0 + row) * 1024;
#pragma unroll
  for (int k = 0; k < 8; ++k) {
    int c = k * 128 + j * 4;
    f32x4 vv;
#pragma unroll
    for (int u = 0; u < 4; ++u)
      vv[u] = __builtin_amdgcn_exp2f(((float)lg[row][c + u] - mx) * 1.44269504088896f) * rinv;
    *(f32x4*)(orow + c) = vv;
  }
}

// ---------------------------------------------------------------------------
extern "C" void kernel_launch(void* const* d_in, const int* in_sizes, int n_in,
                              void* d_out, int out_size, void* d_ws, size_t ws_size,
                              hipStream_t stream) {
  const float* X  = (const float*)d_in[0];
  const float* Wx = (const float*)d_in[1];
  const float* Wh = (const float*)d_in[2];
  const float* bv = (const float*)d_in[3];
  const float* Wd = (const float*)d_in[4];
  const float* bd = (const float*)d_in[5];
  float* out = (float*)d_out;

  char* ws = (char*)d_ws;
  float*    xp_packed = (float*)(ws);                              // 16 MB
  _Float16* Yt    = (_Float16*)(ws + (16u << 20));                 // 8 MB
  _Float16* WxT   = (_Float16*)(ws + (24u << 20));                 // 512 KB
  _Float16* WhT   = (_Float16*)(ws + (24u << 20) + (512u << 10));  // 128 KB
  _Float16* WdT   = (_Float16*)(ws + (24u << 20) + (640u << 10));  // 512 KB

  k_transpose_cast<<<dim3(8, 32), 256, 0, stream>>>(Wx, WxT, 1024, 256);
  k_transpose_cast<<<dim3(8, 8),  256, 0, stream>>>(Wh, WhT, 256, 256);
  k_transpose_cast<<<dim3(32, 8), 256, 0, stream>>>(Wd, WdT, 256, 1024);
  k_gemm1<<<dim3(256), 256, 0, stream>>>(X, WxT, bv, xp_packed);
  k_scan<<<dim3(2), 512, 0, stream>>>(xp_packed, WhT, Yt, out + 16384 * 1024);
  k_gemm3<<<dim3(1024), 512, 0, stream>>>(Yt, WdT, bd, out);
}

// Round 3
// 441.516 us; speedup vs baseline: 1.2511x; 1.0096x over previous
//
#include <hip/hip_runtime.h>

// Sizes fixed by the problem.
#define BB 32
#define TT 512
#define VV 1024
#define HH 256

typedef float f32x4 __attribute__((ext_vector_type(4)));
typedef _Float16 f16x8 __attribute__((ext_vector_type(8)));
typedef _Float16 f16x4 __attribute__((ext_vector_type(4)));

__device__ __forceinline__ float tanh_fast(float x) {
  float e = __builtin_amdgcn_exp2f(x * 2.885390081777927f);
  return 1.0f - 2.0f * __builtin_amdgcn_rcpf(e + 1.0f);
}

// ---------------------------------------------------------------------------
// Transpose + cast fp32 -> f16:  out[C][R] = (f16) in[R][C]
// ---------------------------------------------------------------------------
__global__ __launch_bounds__(256) void k_transpose_cast(
    const float* __restrict__ in, _Float16* __restrict__ outp, int R, int C)
{
  __shared__ float tile[32][33];
  const int tx = threadIdx.x & 31, ty = threadIdx.x >> 5;
  const int tc = blockIdx.x * 32, tr = blockIdx.y * 32;
#pragma unroll
  for (int i = 0; i < 32; i += 8)
    tile[ty + i][tx] = in[(size_t)(tr + ty + i) * C + tc + tx];
  __syncthreads();
#pragma unroll
  for (int i = 0; i < 32; i += 8)
    outp[(size_t)(tc + ty + i) * R + tr + tx] = (_Float16)tile[tx][ty + i];
}

// ---------------------------------------------------------------------------
// GEMM1: xproj = X @ Wx + b, written PACKED for the scan kernel:
//   xp_packed[((t*2+g)*8 + w)*512 + lane*8 + set*4 + r]
//     where b = g*16 + (lane>>4)*4 + r, col = w*32 + set*16 + (lane&15)
// ---------------------------------------------------------------------------
__global__ __launch_bounds__(256) void k_gemm1(
    const float* __restrict__ X, const _Float16* __restrict__ WxT,
    const float* __restrict__ bias, float* __restrict__ xp_packed)
{
  __shared__ _Float16 As[64][72];
  __shared__ _Float16 Bs[256][72];
  const int tid = threadIdx.x;
  const int lane = tid & 63, w = tid >> 6;
  const int l15 = lane & 15, lq = lane >> 4;
  const int m0 = blockIdx.x * 64;

  f32x4 acc[16];
#pragma unroll
  for (int i = 0; i < 16; ++i) acc[i] = (f32x4){0.f, 0.f, 0.f, 0.f};

  for (int kc = 0; kc < 16; ++kc) {
    const int k0 = kc * 64;
#pragma unroll
    for (int it = 0; it < 4; ++it) {
      int q = tid + it * 256;
      int r = q >> 4, k4 = (q & 15) * 4;
      f32x4 v = *(const f32x4*)(X + (size_t)(m0 + r) * 1024 + k0 + k4);
      f16x4 hv;
      hv[0] = (_Float16)v[0]; hv[1] = (_Float16)v[1];
      hv[2] = (_Float16)v[2]; hv[3] = (_Float16)v[3];
      *(f16x4*)(&As[r][k4]) = hv;
    }
#pragma unroll
    for (int it = 0; it < 8; ++it) {
      int q = tid + it * 256;
      int n = q >> 3, k8 = (q & 7) * 8;
      *(f16x8*)(&Bs[n][k8]) = *(const f16x8*)(WxT + (size_t)n * 1024 + k0 + k8);
    }
    __syncthreads();
    f16x8 a[2];
#pragma unroll
    for (int ks = 0; ks < 2; ++ks)
      a[ks] = *(const f16x8*)(&As[w * 16 + l15][ks * 32 + lq * 8]);
#pragma unroll
    for (int ct = 0; ct < 16; ++ct) {
#pragma unroll
      for (int ks = 0; ks < 2; ++ks) {
        f16x8 bfr = *(const f16x8*)(&Bs[ct * 16 + l15][ks * 32 + lq * 8]);
        acc[ct] = __builtin_amdgcn_mfma_f32_16x16x32_f16(a[ks], bfr, acc[ct], 0, 0, 0);
      }
    }
    __syncthreads();
  }
#pragma unroll
  for (int ct = 0; ct < 16; ++ct) {
    int ncol = ct * 16 + l15;
    float bvv = bias[ncol];
    int ws2 = ncol >> 5, set = (ncol >> 4) & 1, c15 = ncol & 15;
#pragma unroll
    for (int r = 0; r < 4; ++r) {
      int m = m0 + w * 16 + lq * 4 + r;     // m = b*512 + t
      int tt = m & 511, bb = m >> 9;
      int g2 = bb >> 4, lq2 = (bb >> 2) & 3, r2 = bb & 3;
      size_t off = ((((size_t)tt * 2 + g2) * 8 + ws2) * 64 + (lq2 * 16 + c15)) * 8
                   + set * 4 + r2;
      xp_packed[off] = acc[ct][r] + bvv;
    }
  }
}

// ---------------------------------------------------------------------------
// RNN scan, VALU-minimized:
//  - h stored in LDS in MFMA-A-FRAGMENT ORDER:
//      byte(row,col) = (col>>5)*1024 + ((col>>3)&3)*256 + row*16 + (col&7)*2
//    -> af reads: 1 base VGPR + immediate ks*1024, conflict-free b128
//    -> epilogue writes: 1 base VGPR + immediates (r*16 + {0,512})
//    -> Y flush: contiguous 16B per thread
//  - acc init = xp directly as first MFMA C operand
//  - raw barrier (lgkmcnt only); peeled step 0 (branch-free flush)
// 2 blocks x 512 threads; block g owns batches g*16..g*16+15.
// ---------------------------------------------------------------------------
__global__ __launch_bounds__(512, 2) void k_scan(
    const float* __restrict__ xp_packed,  // packed, see k_gemm1
    const _Float16* __restrict__ WhT,     // [256][256]
    _Float16* __restrict__ Yt,            // [512][32][256] f16  (t-major)
    float* __restrict__ hT)               // [32][256] fp32
{
  __shared__ char hlds[2][8192];          // two 16x256 f16 h buffers, frag-order
  const int tid = threadIdx.x;
  const int lane = tid & 63, w = tid >> 6;
  const int l15 = lane & 15, lq = lane >> 4;
  const int g = blockIdx.x;

  for (int i = tid; i < 4096; i += 512) ((float*)hlds)[i] = 0.f;

  const int col0 = w * 32 + l15;
  const int col1 = col0 + 16;

  // Wh fragments in registers for the whole scan (64 VGPRs)
  f16x8 bf0[8], bf1[8];
#pragma unroll
  for (int ks = 0; ks < 8; ++ks) {
    bf0[ks] = *(const f16x8*)(WhT + col0 * 256 + ks * 32 + lq * 8);
    bf1[ks] = *(const f16x8*)(WhT + col1 * 256 + ks * 32 + lq * 8);
  }

  char* hzero = (char*)&hlds[0][0];
  // A-fragment read base: row=l15, k-block lq
  const int base_af = lq * 256 + l15 * 16;
  // epilogue write base for (col0,row=lq*4+r): + r*16, col1: +512
  const int base_wr = w * 1024 + (l15 >> 3) * 256 + lq * 64 + (l15 & 7) * 2;
  // flush: thread covers row=tid>>5, col8=(tid&31)*8 -> contiguous 16B
  const int row_f = tid >> 5, grp = tid & 31;
  const int base_fl = (grp >> 2) * 1024 + (grp & 3) * 256 + row_f * 16;

  const float* xpbase = xp_packed + (size_t)g * 4096 + w * 512 + lane * 8;
  // Y flush pointer, first target is Yt[t=0] slot
  char* ybase = (char*)Yt + ((size_t)(g * 16 + row_f)) * 512 + grp * 16;
  float* hTrow = hT + (g * 16 + row_f) * 256 + grp * 8;

  __syncthreads();   // zero-init visible

  // prefetch xp for t=0,1
  f32x4 xa0 = *(const f32x4*)(xpbase);
  f32x4 xb0 = *(const f32x4*)(xpbase + 4);
  f32x4 xa1 = *(const f32x4*)(xpbase + 8192);
  f32x4 xb1 = *(const f32x4*)(xpbase + 8192 + 4);

#define SCAN_STEP(T, CUR, XA, XB, FLUSH)                                       \
  {                                                                            \
    const int t = (T);                                                         \
    /* A fragments: immediate-offset conflict-free reads */                    \
    f16x8 af[8];                                                               \
    _Pragma("unroll")                                                          \
    for (int ks = 0; ks < 8; ++ks)                                             \
      af[ks] = *(const f16x8*)(hzero + base_af + (CUR) * 8192 + ks * 1024);    \
    if (FLUSH) { /* flush h_{t-1} from the buffer we read this step */         \
      f16x8 hv = *(const f16x8*)(hzero + base_fl + (CUR) * 8192);              \
      *(f16x8*)ybase = hv;                                                     \
      ybase += 16384;                                                          \
    }                                                                          \
    f32x4 acc0a = __builtin_amdgcn_mfma_f32_16x16x32_f16(af[0], bf0[0], XA, 0, 0, 0); \
    f32x4 acc1a = __builtin_amdgcn_mfma_f32_16x16x32_f16(af[0], bf1[0], XB, 0, 0, 0); \
    f32x4 zz = {0.f, 0.f, 0.f, 0.f};                                           \
    f32x4 acc0b = __builtin_amdgcn_mfma_f32_16x16x32_f16(af[4], bf0[4], zz, 0, 0, 0); \
    f32x4 acc1b = __builtin_amdgcn_mfma_f32_16x16x32_f16(af[4], bf1[4], zz, 0, 0, 0); \
    { /* prefetch xp for t+2 into the just-freed regs */                       \
      int tn = t + 2; if (tn > 511) tn = 511;                                  \
      const float* p = xpbase + (size_t)tn * 8192;                             \
      XA = *(const f32x4*)p;                                                   \
      XB = *(const f32x4*)(p + 4);                                             \
    }                                                                          \
    _Pragma("unroll")                                                          \
    for (int ks = 1; ks < 4; ++ks) {                                           \
      acc0a = __builtin_amdgcn_mfma_f32_16x16x32_f16(af[ks], bf0[ks], acc0a, 0, 0, 0); \
      acc1a = __builtin_amdgcn_mfma_f32_16x16x32_f16(af[ks], bf1[ks], acc1a, 0, 0, 0); \
      acc0b = __builtin_amdgcn_mfma_f32_16x16x32_f16(af[ks + 4], bf0[ks + 4], acc0b, 0, 0, 0); \
      acc1b = __builtin_amdgcn_mfma_f32_16x16x32_f16(af[ks + 4], bf1[ks + 4], acc1b, 0, 0, 0); \
    }                                                                          \
    /* epilogue: tanh, write h_t to the other buffer (immediates only) */      \
    char* hw = hzero + base_wr + ((CUR) ^ 1) * 8192;                           \
    _Pragma("unroll")                                                          \
    for (int r = 0; r < 4; ++r) {                                              \
      float v0 = tanh_fast(acc0a[r] + acc0b[r]);                               \
      float v1 = tanh_fast(acc1a[r] + acc1b[r]);                               \
      *(_Float16*)(hw + r * 16) = (_Float16)v0;                                \
      *(_Float16*)(hw + r * 16 + 512) = (_Float16)v1;                          \
    }                                                                          \
    asm volatile("s_waitcnt lgkmcnt(0)" ::: "memory");                         \
    __builtin_amdgcn_s_barrier();                                              \
    asm volatile("" ::: "memory");                                             \
  }

  SCAN_STEP(0, 0, xa0, xb0, 0)
  for (int tp = 0; tp < 255; ++tp) {
    SCAN_STEP(2 * tp + 1, 1, xa1, xb1, 1)
    SCAN_STEP(2 * tp + 2, 0, xa0, xb0, 1)
  }
  SCAN_STEP(511, 1, xa1, xb1, 1)
#undef SCAN_STEP

  // h_511 sits in buffer 0; flush to Yt[511] and final state (fp32)
  {
    f16x8 hv = *(const f16x8*)(hzero + base_fl);
    *(f16x8*)ybase = hv;
    f32x4 lo, hi;
#pragma unroll
    for (int u = 0; u < 4; ++u) { lo[u] = (float)hv[u]; hi[u] = (float)hv[u + 4]; }
    *(f32x4*)(hTrow) = lo;
    *(f32x4*)(hTrow + 4) = hi;
  }
}

// ---------------------------------------------------------------------------
// GEMM3 + fused softmax: out = softmax(Y @ Wd + bd)
// ---------------------------------------------------------------------------
__global__ __launch_bounds__(512) void k_gemm3(
    const _Float16* __restrict__ Yt,   // [512][32][256]
    const _Float16* __restrict__ WdT,  // [1024][256]
    const float* __restrict__ bd,      // [1024]
    float* __restrict__ out)           // [16384][1024]
{
  __shared__ _Float16 As[16][264];
  __shared__ _Float16 Bs[128][264];
  __shared__ _Float16 lg[16][1040];
  const int tid = threadIdx.x;
  const int lane = tid & 63, w = tid >> 6;
  const int l15 = lane & 15, lq = lane >> 4;
  const int m0 = blockIdx.x * 16;
  const int b = m0 >> 9, t0 = m0 & 511;

  {
    int r = tid >> 5, k8 = (tid & 31) * 8;
    *(f16x8*)(&As[r][k8]) = *(const f16x8*)(Yt + ((size_t)(t0 + r) * 32 + b) * 256 + k8);
  }
  __syncthreads();
  f16x8 a[8];
#pragma unroll
  for (int ks = 0; ks < 8; ++ks)
    a[ks] = *(const f16x8*)(&As[l15][ks * 32 + lq * 8]);

  for (int cc = 0; cc < 8; ++cc) {
    const int c0 = cc * 128;
    __syncthreads();
#pragma unroll
    for (int i = 0; i < 8; ++i) {
      int q = i * 512 + tid;
      int n = q >> 5, k8 = (q & 31) * 8;
      *(f16x8*)(&Bs[n][k8]) = *(const f16x8*)(WdT + (size_t)(c0 + n) * 256 + k8);
    }
    __syncthreads();
    int ncol = c0 + w * 16 + l15;
    f32x4 acc = {0.f, 0.f, 0.f, 0.f};
#pragma unroll
    for (int ks = 0; ks < 8; ++ks) {
      f16x8 bfr = *(const f16x8*)(&Bs[w * 16 + l15][ks * 32 + lq * 8]);
      acc = __builtin_amdgcn_mfma_f32_16x16x32_f16(a[ks], bfr, acc, 0, 0, 0);
    }
    float bvv = bd[ncol];
#pragma unroll
    for (int r = 0; r < 4; ++r)
      lg[lq * 4 + r][ncol] = (_Float16)(acc[r] + bvv);
  }
  __syncthreads();

  const int row = tid >> 5, j = tid & 31;
  float mx = -1e30f;
#pragma unroll
  for (int k = 0; k < 32; ++k)
    mx = fmaxf(mx, (float)lg[row][j + k * 32]);
#pragma unroll
  for (int m = 1; m < 32; m <<= 1)
    mx = fmaxf(mx, __shfl_xor(mx, m, 64));
  float s = 0.f;
#pragma unroll
  for (int k = 0; k < 32; ++k)
    s += __builtin_amdgcn_exp2f(((float)lg[row][j + k * 32] - mx) * 1.44269504088896f);
#pragma unroll
  for (int m = 1; m < 32; m <<= 1)
    s += __shfl_xor(s, m, 64);
  const float rinv = __builtin_amdgcn_rcpf(s);
  float* orow = out + (size_t)(m0 + row) * 1024;
#pragma unroll
  for (int k = 0; k < 8; ++k) {
    int c = k * 128 + j * 4;
    f32x4 vv;
#pragma unroll
    for (int u = 0; u < 4; ++u)
      vv[u] = __builtin_amdgcn_exp2f(((float)lg[row][c + u] - mx) * 1.44269504088896f) * rinv;
    *(f32x4*)(orow + c) = vv;
  }
}

// ---------------------------------------------------------------------------
extern "C" void kernel_launch(void* const* d_in, const int* in_sizes, int n_in,
                              void* d_out, int out_size, void* d_ws, size_t ws_size,
                              hipStream_t stream) {
  const float* X  = (const float*)d_in[0];
  const float* Wx = (const float*)d_in[1];
  const float* Wh = (const float*)d_in[2];
  const float* bv = (const float*)d_in[3];
  const float* Wd = (const float*)d_in[4];
  const float* bd = (const float*)d_in[5];
  float* out = (float*)d_out;

  char* ws = (char*)d_ws;
  float*    xp_packed = (float*)(ws);                              // 16 MB
  _Float16* Yt    = (_Float16*)(ws + (16u << 20));                 // 8 MB
  _Float16* WxT   = (_Float16*)(ws + (24u << 20));                 // 512 KB
  _Float16* WhT   = (_Float16*)(ws + (24u << 20) + (512u << 10));  // 128 KB
  _Float16* WdT   = (_Float16*)(ws + (24u << 20) + (640u << 10));  // 512 KB

  k_transpose_cast<<<dim3(8, 32), 256, 0, stream>>>(Wx, WxT, 1024, 256);
  k_transpose_cast<<<dim3(8, 8),  256, 0, stream>>>(Wh, WhT, 256, 256);
  k_transpose_cast<<<dim3(32, 8), 256, 0, stream>>>(Wd, WdT, 256, 1024);
  k_gemm1<<<dim3(256), 256, 0, stream>>>(X, WxT, bv, xp_packed);
  k_scan<<<dim3(2), 512, 0, stream>>>(xp_packed, WhT, Yt, out + 16384 * 1024);
  k_gemm3<<<dim3(1024), 512, 0, stream>>>(Yt, WdT, bd, out);
}